// Round 11
// baseline (220.033 us; speedup 1.0000x reference)
//
#include <hip/hip_runtime.h>
#include <math.h>

// ---------------------------------------------------------------------------
// GCN 3-layer on MI355X.  (round-8 config + fused scan)
// CSR build = two-level histogram sort (no contended global atomics):
//   A: 196 chunk-blocks histogram dst>>8 into 196 buckets (LDS), -> Gh[buk][blk]
//   S12: ONE block: per-bucket row sums + scan -> absolute (bucket,block)
//        offsets rowoff, bucket bases rowbase
//   B (fused w/ GEMM1): chunk re-read, LDS-atomic rank, write packed
//      (dloc<<16|src) into private (bucket,block) segment (~1.3x write amp)
//   C: per-bucket block: 256-bin LDS hist+scan -> row_beg/row_end/dinv,
//      scatter col (u16) into bucket-contiguous range (L2-local)
// GEMMs: bf16 MFMA 16x16x32, BM=64 (782 blocks: best tail packing on 256 CUs;
// BM=128 measured slower, round 10). GEMM1 unscaled + weighted agg1;
// GEMM2/3 fold dinv into epilogue (z'=z*dinv) + weight-free agg.
// Agg: 1 wave/node, LPN=F/8 lanes, SLOTS=64/LPN (2-wave/node slower, round 9:
// aggs are L3 random-gather service-bound ~7 TB/s, not latency-chain bound).
// ---------------------------------------------------------------------------

#define NFEAT 512
#define NHID  128
#define NCLS  64
#define CHUNK 4096
#define CAPC  6656   // per-bucket stash (mean 4082, sd 64 -> +40 sigma)

typedef __attribute__((ext_vector_type(8))) short bf16x8;
typedef __attribute__((ext_vector_type(8))) unsigned short u16x8;
typedef __attribute__((ext_vector_type(4))) float f32x4;

__device__ __forceinline__ unsigned short f2bf(float f) {
  unsigned u = __builtin_bit_cast(unsigned, f);
  unsigned r = (u + 0x7FFFu + ((u >> 16) & 1u)) >> 16;
  return (unsigned short)r;
}
__device__ __forceinline__ float bf2f(unsigned short u) {
  return __builtin_bit_cast(float, (unsigned)u << 16);
}

// --------------------- W transpose + cast (device body) --------------------
__device__ __forceinline__ void wcast_body(const float* __restrict__ W,
                                           unsigned short* __restrict__ Wt,
                                           int K, int N, int bid) {
  int idx = bid * 256 + threadIdx.x;
  if (idx >= N * K) return;
  int n = idx / K;
  int k = idx - n * K;
  Wt[idx] = f2bf(W[(size_t)k * N + n]);
}

// ------------------ A: chunk histograms (+ wcast riders) -------------------
__global__ void histA_wcast_kernel(const int* __restrict__ dst, int E, int CB, int NBUKr,
                                   int* __restrict__ Gh,
                                   const float* __restrict__ W1, unsigned short* __restrict__ Wt1,
                                   const float* __restrict__ W2, unsigned short* __restrict__ Wt2,
                                   const float* __restrict__ W3, unsigned short* __restrict__ Wt3) {
  int blk = blockIdx.x;
  if (blk >= CB) {
    int b = blk - CB;
    if (b < 256) { wcast_body(W1, Wt1, NFEAT, NHID, b); return; }
    b -= 256;
    if (b < 64) { wcast_body(W2, Wt2, NHID, NHID, b); return; }
    b -= 64;
    wcast_body(W3, Wt3, NHID, NCLS, b);
    return;
  }
  __shared__ int hist[256];
  const int t = threadIdx.x;
  hist[t] = 0;
  __syncthreads();
  const int E4 = E >> 2;
  const int4* dst4 = (const int4*)dst;
  const int base4 = blk * (CHUNK / 4);
#pragma unroll
  for (int i = 0; i < CHUNK / 4 / 256; ++i) {
    int idx = base4 + t + i * 256;
    if (idx < E4) {
      int4 d = dst4[idx];
      atomicAdd(&hist[d.x >> 8], 1);
      atomicAdd(&hist[d.y >> 8], 1);
      atomicAdd(&hist[d.z >> 8], 1);
      atomicAdd(&hist[d.w >> 8], 1);
    }
  }
  if (blk == 0 && t < (E & 3)) atomicAdd(&hist[dst[(E & ~3) + t] >> 8], 1);
  __syncthreads();
  if (t < NBUKr) Gh[t * CB + blk] = hist[t];
}

// ---- S12: one block: row sums + block scan -> absolute rowoff, rowbase ----
__global__ void s12_kernel(const int* __restrict__ Gh, int* __restrict__ rowoff,
                           int* __restrict__ rowbase, int CB, int NBUKr) {
  const int t = threadIdx.x;
  int tot = 0;
  if (t < NBUKr) {
    for (int b = 0; b < CB; ++b) tot += Gh[t * CB + b];
  }
  __shared__ int sh[256];
  sh[t] = tot;
  __syncthreads();
  for (int off = 1; off < 256; off <<= 1) {
    int u = (t >= off) ? sh[t - off] : 0;
    __syncthreads();
    sh[t] += u;
    __syncthreads();
  }
  int base = sh[t] - tot;  // exclusive prefix = bucket base
  if (t < NBUKr) {
    rowbase[t] = base;
    int run = base;
    for (int b = 0; b < CB; ++b) {
      rowoff[t * CB + b] = run;       // ABSOLUTE offset for (bucket t, block b)
      run += Gh[t * CB + b];
    }
  }
  if (t == NBUKr - 1) rowbase[NBUKr] = base + tot;
}

// --------------------------- GEMM body (device) ----------------------------
// C[M,BN](bf16) = (A[M,K] @ Wt[BN,K]) [* dinv[row] if SCALE].  BM=BK=64.
template <int BN, bool A_BF16, bool SCALE>
__device__ __forceinline__ void gemm_body(const void* __restrict__ Av,
                                          const unsigned short* __restrict__ Wt,
                                          const float* __restrict__ dinv,
                                          unsigned short* __restrict__ C,
                                          int M, int K, int bid) {
  constexpr int BM = 64, BK = 64;
  constexpr int NF = BN / 32;
  __shared__ unsigned short Al[BM * BK];
  __shared__ unsigned short Bl[(BN > BM ? BN : BM) * BK];
  const int tid = threadIdx.x;
  const int lane = tid & 63;
  const int wave = tid >> 6;
  const int wm = wave >> 1, wn = wave & 1;
  const int block_row = bid * BM;

  f32x4 acc[2][NF];
#pragma unroll
  for (int i = 0; i < 2; ++i)
#pragma unroll
    for (int j = 0; j < NF; ++j) acc[i][j] = (f32x4){0.f, 0.f, 0.f, 0.f};

  for (int k0 = 0; k0 < K; k0 += BK) {
    if constexpr (!A_BF16) {
      const float* A = (const float*)Av;
      const int r = tid >> 2;
      const int c0 = (tid & 3) * 16;
      const int grow = block_row + r;
      float4 v[4];
      if (grow < M) {
        const float4* p = reinterpret_cast<const float4*>(&A[(size_t)grow * K + k0 + c0]);
        v[0] = p[0]; v[1] = p[1]; v[2] = p[2]; v[3] = p[3];
      } else {
        v[0] = v[1] = v[2] = v[3] = make_float4(0.f, 0.f, 0.f, 0.f);
      }
      unsigned short tbuf[16];
#pragma unroll
      for (int q = 0; q < 4; ++q) {
        tbuf[q * 4 + 0] = f2bf(v[q].x); tbuf[q * 4 + 1] = f2bf(v[q].y);
        tbuf[q * 4 + 2] = f2bf(v[q].z); tbuf[q * 4 + 3] = f2bf(v[q].w);
      }
#pragma unroll
      for (int h = 0; h < 2; ++h) {
        int c = c0 + h * 8;
        int byte = r * 128 + c * 2;
        byte ^= (r & 7) << 4;
        u16x8 pk;
#pragma unroll
        for (int q = 0; q < 8; ++q) pk[q] = tbuf[h * 8 + q];
        *reinterpret_cast<u16x8*>(reinterpret_cast<char*>(Al) + byte) = pk;
      }
    } else {
      const unsigned short* A = (const unsigned short*)Av;
#pragma unroll
      for (int l = 0; l < 2; ++l) {
        int vidx = tid + l * 256;
        int r = vidx >> 3;
        int kc = (vidx & 7) * 8;
        int grow = block_row + r;
        u16x8 pk = (u16x8){0, 0, 0, 0, 0, 0, 0, 0};
        if (grow < M) pk = *reinterpret_cast<const u16x8*>(&A[(size_t)grow * K + k0 + kc]);
        int byte = r * 128 + kc * 2;
        byte ^= (r & 7) << 4;
        *reinterpret_cast<u16x8*>(reinterpret_cast<char*>(Al) + byte) = pk;
      }
    }
    {
#pragma unroll
      for (int l = 0; l < (BN * BK / 8) / 256; ++l) {
        int vidx = tid + l * 256;
        int n = vidx >> 3;
        int kc = (vidx & 7) * 8;
        u16x8 pk = *reinterpret_cast<const u16x8*>(&Wt[(size_t)n * K + k0 + kc]);
        int byte = n * 128 + kc * 2;
        byte ^= (n & 7) << 4;
        *reinterpret_cast<u16x8*>(reinterpret_cast<char*>(Bl) + byte) = pk;
      }
    }
    __syncthreads();
#pragma unroll
    for (int kk = 0; kk < 2; ++kk) {
      const int kb = kk * 32 + (lane >> 4) * 8;
      bf16x8 af[2], bfr[NF];
#pragma unroll
      for (int mf = 0; mf < 2; ++mf) {
        int r = wm * 32 + mf * 16 + (lane & 15);
        int byte = r * 128 + kb * 2;
        byte ^= (r & 7) << 4;
        af[mf] = *reinterpret_cast<bf16x8*>(reinterpret_cast<char*>(Al) + byte);
      }
#pragma unroll
      for (int nf = 0; nf < NF; ++nf) {
        int n = wn * (BN / 2) + nf * 16 + (lane & 15);
        int byte = n * 128 + kb * 2;
        byte ^= (n & 7) << 4;
        bfr[nf] = *reinterpret_cast<bf16x8*>(reinterpret_cast<char*>(Bl) + byte);
      }
#pragma unroll
      for (int mf = 0; mf < 2; ++mf)
#pragma unroll
        for (int nf = 0; nf < NF; ++nf)
          acc[mf][nf] = __builtin_amdgcn_mfma_f32_16x16x32_bf16(af[mf], bfr[nf], acc[mf][nf], 0, 0, 0);
    }
    __syncthreads();
  }
#pragma unroll
  for (int mf = 0; mf < 2; ++mf) {
#pragma unroll
    for (int r = 0; r < 4; ++r) {
      int row = block_row + wm * 32 + mf * 16 + (lane >> 4) * 4 + r;
      if (row < M) {
        float dr = 1.f;
        if constexpr (SCALE) dr = dinv[row];
#pragma unroll
        for (int nf = 0; nf < NF; ++nf) {
          int colc = wn * (BN / 2) + nf * 16 + (lane & 15);
          float v = acc[mf][nf][r];
          if constexpr (SCALE) v *= dr;
          C[(size_t)row * BN + colc] = f2bf(v);
        }
      }
    }
  }
}

template <int BN, bool A_BF16, bool SCALE>
__global__ void mfma_gemm_kernel(const void* __restrict__ Av,
                                 const unsigned short* __restrict__ Wt,
                                 const float* __restrict__ dinv,
                                 unsigned short* __restrict__ C, int M, int K) {
  gemm_body<BN, A_BF16, SCALE>(Av, Wt, dinv, C, M, K, blockIdx.x);
}

// -------------- B: staged scatter into private segments (device) -----------
__device__ __forceinline__ void scatterB_body(const int* __restrict__ src,
                                              const int* __restrict__ dst,
                                              int E, int CB, int NBUKr,
                                              const int* __restrict__ rowoff,
                                              unsigned* __restrict__ stage, int blk) {
  __shared__ int pos[256];
  const int t = threadIdx.x;
  if (t < NBUKr) pos[t] = rowoff[t * CB + blk];  // absolute offsets
  __syncthreads();
  const int E4 = E >> 2;
  const int4* dst4 = (const int4*)dst;
  const int4* src4 = (const int4*)src;
  const int base4 = blk * (CHUNK / 4);
#pragma unroll
  for (int i = 0; i < CHUNK / 4 / 256; ++i) {
    int idx = base4 + t + i * 256;
    if (idx < E4) {
      int4 d = dst4[idx];
      int4 s = src4[idx];
      int p;
      p = atomicAdd(&pos[d.x >> 8], 1); stage[p] = ((unsigned)(d.x & 255) << 16) | (unsigned)s.x;
      p = atomicAdd(&pos[d.y >> 8], 1); stage[p] = ((unsigned)(d.y & 255) << 16) | (unsigned)s.y;
      p = atomicAdd(&pos[d.z >> 8], 1); stage[p] = ((unsigned)(d.z & 255) << 16) | (unsigned)s.z;
      p = atomicAdd(&pos[d.w >> 8], 1); stage[p] = ((unsigned)(d.w & 255) << 16) | (unsigned)s.w;
    }
  }
  if (blk == 0 && t < (E & 3)) {
    int e = (E & ~3) + t;
    int d = dst[e], s = src[e];
    int p = atomicAdd(&pos[d >> 8], 1);
    stage[p] = ((unsigned)(d & 255) << 16) | (unsigned)s;
  }
}

__global__ void gemm1_scatter_kernel(const float* __restrict__ x,
                                     const unsigned short* __restrict__ Wt1,
                                     unsigned short* __restrict__ C, int M,
                                     const int* __restrict__ src, const int* __restrict__ dst,
                                     int E, int CB, int NBUKr,
                                     const int* __restrict__ rowoff,
                                     unsigned* __restrict__ stage) {
  if ((int)blockIdx.x < CB) {
    scatterB_body(src, dst, E, CB, NBUKr, rowoff, stage, blockIdx.x);
  } else {
    gemm_body<128, false, false>(x, Wt1, nullptr, C, M, NFEAT, blockIdx.x - CB);
  }
}

// ------------- C: per-bucket node sort -> row ranges, col, dinv ------------
__global__ void phaseC_kernel(const unsigned* __restrict__ stage,
                              const int* __restrict__ rowbase,
                              int* __restrict__ row_beg, int* __restrict__ row_end,
                              unsigned short* __restrict__ col, float* __restrict__ dinv,
                              int N) {
  const int k = blockIdx.x;
  const int start = rowbase[k];
  const int cnt = rowbase[k + 1] - start;
  const int node0 = k << 8;
  const int t = threadIdx.x;
  __shared__ int hist[256], lpos[256], wsum[4];
  __shared__ unsigned stash[CAPC];
  hist[t] = 0;
  __syncthreads();
  for (int i = t; i < cnt; i += 256) {
    unsigned v = stage[start + i];
    if (i < CAPC) stash[i] = v;
    atomicAdd(&hist[v >> 16], 1);
  }
  __syncthreads();
  int a = hist[t];
  const int lane = t & 63, wid = t >> 6;
  int incl = a;
#pragma unroll
  for (int off = 1; off < 64; off <<= 1) {
    int u = __shfl_up(incl, off);
    if (lane >= off) incl += u;
  }
  if (lane == 63) wsum[wid] = incl;
  __syncthreads();
  int wo = 0;
#pragma unroll
  for (int w = 0; w < 4; ++w)
    if (w < wid) wo += wsum[w];
  int excl = wo + incl - a;
  lpos[t] = excl;
  int node = node0 + t;
  if (node < N) {
    row_beg[node] = start + excl;
    row_end[node] = start + excl + a;
    dinv[node] = rsqrtf((float)(a + 1));
  }
  __syncthreads();
  for (int i = t; i < cnt; i += 256) {
    unsigned v = (i < CAPC) ? stash[i] : stage[start + i];
    int p = atomicAdd(&lpos[v >> 16], 1);
    col[start + p] = (unsigned short)(v & 0xFFFFu);
  }
}

// ----------------------------- aggregation ---------------------------------
// 1 wave/node, LPN=F/8 lanes per edge-row, SLOTS=64/LPN.
// WEIGHTED: out = di*( sum_j dinv[col_j]*z[col_j] + di*z[i] ) + b
// else (z pre-scaled): out = di*( sum_j z'[col_j] + z'[i] ) + b
template <int F, int RELU, bool OUT_BF16, bool WEIGHTED>
__global__ void agg_kernel(const unsigned short* __restrict__ H,
                           const int* __restrict__ row_beg, const int* __restrict__ row_end,
                           const unsigned short* __restrict__ col,
                           const float* __restrict__ dinv, const float* __restrict__ bias,
                           void* __restrict__ out, int N) {
  constexpr int LPN = F / 8;
  constexpr int SLOTS = 64 / LPN;
  const int tid = threadIdx.x;
  const int lane = tid & 63;
  const int li = lane & (LPN - 1);
  const int slot = lane / LPN;
  const int node = blockIdx.x * 4 + (tid >> 6);
  if (node >= N) return;
  const float di = dinv[node];
  const u16x8* Hv = reinterpret_cast<const u16x8*>(H);
  u16x8 h0 = Hv[(size_t)node * LPN + li];

  float s[8];
#pragma unroll
  for (int q = 0; q < 8; ++q) s[q] = 0.f;

  const int beg = row_beg[node];
  const int end = row_end[node];
  int j = beg + slot;
  for (; j + 3 * SLOTS < end; j += 4 * SLOTS) {
    int i0 = col[j], i1 = col[j + SLOTS], i2 = col[j + 2 * SLOTS], i3 = col[j + 3 * SLOTS];
    float w0 = 1.f, w1 = 1.f, w2 = 1.f, w3 = 1.f;
    if constexpr (WEIGHTED) { w0 = dinv[i0]; w1 = dinv[i1]; w2 = dinv[i2]; w3 = dinv[i3]; }
    u16x8 r0 = Hv[(size_t)i0 * LPN + li];
    u16x8 r1 = Hv[(size_t)i1 * LPN + li];
    u16x8 r2 = Hv[(size_t)i2 * LPN + li];
    u16x8 r3 = Hv[(size_t)i3 * LPN + li];
    if constexpr (WEIGHTED) {
#pragma unroll
      for (int q = 0; q < 8; ++q)
        s[q] += bf2f(r0[q]) * w0 + bf2f(r1[q]) * w1 + bf2f(r2[q]) * w2 + bf2f(r3[q]) * w3;
    } else {
#pragma unroll
      for (int q = 0; q < 8; ++q)
        s[q] += (bf2f(r0[q]) + bf2f(r1[q])) + (bf2f(r2[q]) + bf2f(r3[q]));
    }
  }
  for (; j < end; j += SLOTS) {
    int i0 = col[j];
    float w0 = 1.f;
    if constexpr (WEIGHTED) w0 = dinv[i0];
    u16x8 r0 = Hv[(size_t)i0 * LPN + li];
    if constexpr (WEIGHTED) {
#pragma unroll
      for (int q = 0; q < 8; ++q) s[q] += bf2f(r0[q]) * w0;
    } else {
#pragma unroll
      for (int q = 0; q < 8; ++q) s[q] += bf2f(r0[q]);
    }
  }
#pragma unroll
  for (int off = LPN; off < 64; off <<= 1) {
#pragma unroll
    for (int q = 0; q < 8; ++q) s[q] += __shfl_xor(s[q], off);
  }
  if (slot == 0) {
    const float4* bv = reinterpret_cast<const float4*>(bias) + li * 2;
    float4 b0 = bv[0], b1 = bv[1];
    float sv[8];
#pragma unroll
    for (int q = 0; q < 8; ++q) {
      float self = WEIGHTED ? bf2f(h0[q]) * di : bf2f(h0[q]);
      sv[q] = (s[q] + self) * di;
    }
    sv[0] += b0.x; sv[1] += b0.y; sv[2] += b0.z; sv[3] += b0.w;
    sv[4] += b1.x; sv[5] += b1.y; sv[6] += b1.z; sv[7] += b1.w;
    if (RELU) {
#pragma unroll
      for (int q = 0; q < 8; ++q) sv[q] = fmaxf(sv[q], 0.f);
    }
    if constexpr (OUT_BF16) {
      u16x8 pk;
#pragma unroll
      for (int q = 0; q < 8; ++q) pk[q] = f2bf(sv[q]);
      reinterpret_cast<u16x8*>(out)[(size_t)node * LPN + li] = pk;
    } else {
      float4* ov = reinterpret_cast<float4*>(out) + (size_t)node * LPN * 2 + li * 2;
      ov[0] = make_float4(sv[0], sv[1], sv[2], sv[3]);
      ov[1] = make_float4(sv[4], sv[5], sv[6], sv[7]);
    }
  }
}

// ----------------- fused agg (F=64) + log_softmax --------------------------
__global__ void agg_ls_kernel(const unsigned short* __restrict__ H,
                              const int* __restrict__ row_beg, const int* __restrict__ row_end,
                              const unsigned short* __restrict__ col,
                              const float* __restrict__ dinv, const float* __restrict__ bias,
                              float* __restrict__ out, int N) {
  constexpr int LPN = 8;
  constexpr int SLOTS = 8;
  const int tid = threadIdx.x;
  const int lane = tid & 63;
  const int li = lane & (LPN - 1);
  const int slot = lane / LPN;
  const int node = blockIdx.x * 4 + (tid >> 6);
  if (node >= N) return;
  const float di = dinv[node];
  const u16x8* Hv = reinterpret_cast<const u16x8*>(H);
  u16x8 h0 = Hv[(size_t)node * LPN + li];

  float s[8];
#pragma unroll
  for (int q = 0; q < 8; ++q) s[q] = 0.f;

  const int beg = row_beg[node];
  const int end = row_end[node];
  int j = beg + slot;
  for (; j + 3 * SLOTS < end; j += 4 * SLOTS) {
    int i0 = col[j], i1 = col[j + SLOTS], i2 = col[j + 2 * SLOTS], i3 = col[j + 3 * SLOTS];
    u16x8 r0 = Hv[(size_t)i0 * LPN + li];
    u16x8 r1 = Hv[(size_t)i1 * LPN + li];
    u16x8 r2 = Hv[(size_t)i2 * LPN + li];
    u16x8 r3 = Hv[(size_t)i3 * LPN + li];
#pragma unroll
    for (int q = 0; q < 8; ++q)
      s[q] += (bf2f(r0[q]) + bf2f(r1[q])) + (bf2f(r2[q]) + bf2f(r3[q]));
  }
  for (; j < end; j += SLOTS) {
    int i0 = col[j];
    u16x8 r0 = Hv[(size_t)i0 * LPN + li];
#pragma unroll
    for (int q = 0; q < 8; ++q) s[q] += bf2f(r0[q]);
  }
#pragma unroll
  for (int off = LPN; off < 64; off <<= 1) {
#pragma unroll
    for (int q = 0; q < 8; ++q) s[q] += __shfl_xor(s[q], off);
  }
  float v[8];
  const float4* bv = reinterpret_cast<const float4*>(bias) + li * 2;
  float4 b0 = bv[0], b1 = bv[1];
#pragma unroll
  for (int q = 0; q < 8; ++q) v[q] = (s[q] + bf2f(h0[q])) * di;
  v[0] += b0.x; v[1] += b0.y; v[2] += b0.z; v[3] += b0.w;
  v[4] += b1.x; v[5] += b1.y; v[6] += b1.z; v[7] += b1.w;
  float m = v[0];
#pragma unroll
  for (int q = 1; q < 8; ++q) m = fmaxf(m, v[q]);
#pragma unroll
  for (int off = 1; off < 8; off <<= 1) m = fmaxf(m, __shfl_xor(m, off));
  float es = 0.f;
#pragma unroll
  for (int q = 0; q < 8; ++q) es += expf(v[q] - m);
#pragma unroll
  for (int off = 1; off < 8; off <<= 1) es += __shfl_xor(es, off);
  if (slot == 0) {
    float lse = m + logf(es);
    float4* ov = reinterpret_cast<float4*>(out) + (size_t)node * 16 + li * 2;
    ov[0] = make_float4(v[0] - lse, v[1] - lse, v[2] - lse, v[3] - lse);
    ov[1] = make_float4(v[4] - lse, v[5] - lse, v[6] - lse, v[7] - lse);
  }
}

// ---------------------------------------------------------------------------
extern "C" void kernel_launch(void* const* d_in, const int* in_sizes, int n_in,
                              void* d_out, int out_size, void* d_ws, size_t ws_size,
                              hipStream_t stream) {
  const float* x  = (const float*)d_in[0];
  const int*   ei = (const int*)d_in[1];
  const float* W1 = (const float*)d_in[2];
  const float* b1 = (const float*)d_in[3];
  const float* W2 = (const float*)d_in[4];
  const float* b2 = (const float*)d_in[5];
  const float* W3 = (const float*)d_in[6];
  const float* b3 = (const float*)d_in[7];
  float* out = (float*)d_out;

  const int N = in_sizes[0] / NFEAT;  // 50000
  const int E = in_sizes[1] / 2;      // 800000
  const int* src = ei;
  const int* dst = ei + E;

  const int NBUKr = (N + 255) >> 8;            // 196 buckets (dst>>8)
  const int CB    = (E + CHUNK - 1) / CHUNK;   // 196 chunk blocks

  char* ws = (char*)d_ws;
  size_t off = 0;
  auto nxt = [&](size_t bytes) -> void* {
    void* p = ws + off;
    off += (bytes + 255) & ~(size_t)255;
    return p;
  };
  int*      Gh      = (int*)nxt((size_t)NBUKr * CB * 4);
  int*      rowoff  = (int*)nxt((size_t)NBUKr * CB * 4);
  int*      rowbase = (int*)nxt((size_t)(NBUKr + 1) * 4);
  unsigned* stage   = (unsigned*)nxt((size_t)E * 4);
  int*      row_beg = (int*)nxt((size_t)N * 4);
  int*      row_end = (int*)nxt((size_t)N * 4);
  unsigned short* col = (unsigned short*)nxt((size_t)E * 2);
  float*    dinv    = (float*)nxt((size_t)N * 4);
  unsigned short* zbuf = (unsigned short*)nxt((size_t)N * NHID * 2);
  unsigned short* hb16 = (unsigned short*)nxt((size_t)N * NHID * 2);
  unsigned short* Wt1 = (unsigned short*)nxt((size_t)NHID * NFEAT * 2);
  unsigned short* Wt2 = (unsigned short*)nxt((size_t)NHID * NHID * 2);
  unsigned short* Wt3 = (unsigned short*)nxt((size_t)NCLS * NHID * 2);
  (void)ws_size; (void)n_in; (void)out_size;

  const int GB = (N + 63) / 64;    // 782 GEMM blocks (BM=64)
  const int ablocks = (N + 3) / 4;

  // A: chunk histograms + wcast riders
  histA_wcast_kernel<<<CB + 256 + 64 + 32, 256, 0, stream>>>(
      dst, E, CB, NBUKr, Gh, W1, Wt1, W2, Wt2, W3, Wt3);
  // S12: fused scan -> absolute segment offsets
  s12_kernel<<<1, 256, 0, stream>>>(Gh, rowoff, rowbase, CB, NBUKr);
  // B (scatter into private segments) fused with GEMM1 (BM=64, unscaled)
  gemm1_scatter_kernel<<<CB + GB, 256, 0, stream>>>(
      x, Wt1, zbuf, N, src, dst, E, CB, NBUKr, rowoff, stage);
  // C: per-bucket finalize -> row ranges, col(u16), dinv
  phaseC_kernel<<<NBUKr, 256, 0, stream>>>(stage, rowbase, row_beg, row_end, col, dinv, N);

  // layer 1 (weighted agg: z unscaled, dinv[col] gather L2-hot)
  agg_kernel<128, 1, true, true><<<ablocks, 256, 0, stream>>>(
      zbuf, row_beg, row_end, col, dinv, b1, hb16, N);
  // layer 2
  mfma_gemm_kernel<128, true, true><<<GB, 256, 0, stream>>>(hb16, Wt2, dinv, zbuf, N, NHID);
  agg_kernel<128, 1, true, false><<<ablocks, 256, 0, stream>>>(
      zbuf, row_beg, row_end, col, dinv, b2, hb16, N);
  // layer 3
  mfma_gemm_kernel<64, true, true><<<GB, 256, 0, stream>>>(hb16, Wt3, dinv, zbuf, N, NHID);
  agg_ls_kernel<<<ablocks, 256, 0, stream>>>(zbuf, row_beg, row_end, col, dinv, b3, out, N);
}

// Round 12
// 160.847 us; speedup vs baseline: 1.3680x; 1.3680x over previous
//
#include <hip/hip_runtime.h>
#include <math.h>

// ---------------------------------------------------------------------------
// GCN 3-layer on MI355X.  (round-8 measured optimum: 161.5 us)
// CSR build = two-level histogram sort (no contended global atomics):
//   A: 196 chunk-blocks histogram dst>>8 into 196 buckets (LDS), -> Gh[buk][blk]
//   S1: per-bucket scan across blocks (196 PARALLEL blocks; 1-block fused
//       variant measured 64 us — round 11); S2: scan bucket totals
//   B (fused w/ GEMM1): chunk re-read, LDS-atomic rank, write packed
//      (dloc<<16|src) into private (bucket,block) segment (~1.3x write amp)
//   C: per-bucket block: 256-bin LDS hist+scan -> row_beg/row_end/dinv,
//      scatter col (u16) into bucket-contiguous range (L2-local)
// GEMMs: bf16 MFMA 16x16x32, BM=64 (BM=128 slower: tail quantization, r10).
// GEMM1 unscaled + weighted agg1; GEMM2/3 fold dinv into epilogue.
// Agg: 1 wave/node, LPN=F/8, SLOTS=64/LPN (2-wave/node slower: L3 gather
// service-bound, r9).
// ---------------------------------------------------------------------------

#define NFEAT 512
#define NHID  128
#define NCLS  64
#define CHUNK 4096
#define CAPC  6656   // per-bucket stash (mean 4082, sd 64 -> +40 sigma)

typedef __attribute__((ext_vector_type(8))) short bf16x8;
typedef __attribute__((ext_vector_type(8))) unsigned short u16x8;
typedef __attribute__((ext_vector_type(4))) float f32x4;

__device__ __forceinline__ unsigned short f2bf(float f) {
  unsigned u = __builtin_bit_cast(unsigned, f);
  unsigned r = (u + 0x7FFFu + ((u >> 16) & 1u)) >> 16;
  return (unsigned short)r;
}
__device__ __forceinline__ float bf2f(unsigned short u) {
  return __builtin_bit_cast(float, (unsigned)u << 16);
}

// --------------------- W transpose + cast (device body) --------------------
__device__ __forceinline__ void wcast_body(const float* __restrict__ W,
                                           unsigned short* __restrict__ Wt,
                                           int K, int N, int bid) {
  int idx = bid * 256 + threadIdx.x;
  if (idx >= N * K) return;
  int n = idx / K;
  int k = idx - n * K;
  Wt[idx] = f2bf(W[(size_t)k * N + n]);
}

// ------------------ A: chunk histograms (+ wcast riders) -------------------
__global__ void histA_wcast_kernel(const int* __restrict__ dst, int E, int CB, int NBUKr,
                                   int* __restrict__ Gh,
                                   const float* __restrict__ W1, unsigned short* __restrict__ Wt1,
                                   const float* __restrict__ W2, unsigned short* __restrict__ Wt2,
                                   const float* __restrict__ W3, unsigned short* __restrict__ Wt3) {
  int blk = blockIdx.x;
  if (blk >= CB) {
    int b = blk - CB;
    if (b < 256) { wcast_body(W1, Wt1, NFEAT, NHID, b); return; }
    b -= 256;
    if (b < 64) { wcast_body(W2, Wt2, NHID, NHID, b); return; }
    b -= 64;
    wcast_body(W3, Wt3, NHID, NCLS, b);
    return;
  }
  __shared__ int hist[256];
  const int t = threadIdx.x;
  hist[t] = 0;
  __syncthreads();
  const int E4 = E >> 2;
  const int4* dst4 = (const int4*)dst;
  const int base4 = blk * (CHUNK / 4);
#pragma unroll
  for (int i = 0; i < CHUNK / 4 / 256; ++i) {
    int idx = base4 + t + i * 256;
    if (idx < E4) {
      int4 d = dst4[idx];
      atomicAdd(&hist[d.x >> 8], 1);
      atomicAdd(&hist[d.y >> 8], 1);
      atomicAdd(&hist[d.z >> 8], 1);
      atomicAdd(&hist[d.w >> 8], 1);
    }
  }
  if (blk == 0 && t < (E & 3)) atomicAdd(&hist[dst[(E & ~3) + t] >> 8], 1);
  __syncthreads();
  if (t < NBUKr) Gh[t * CB + blk] = hist[t];
}

// --------- S1: exclusive scan of each bucket row across CB blocks ----------
__global__ void s1_kernel(const int* __restrict__ Gh, int* __restrict__ rowoff,
                          int* __restrict__ rowtot, int CB) {
  const int k = blockIdx.x;
  const int t = threadIdx.x;
  const int lane = t & 63, wid = t >> 6;
  int a = (t < CB) ? Gh[k * CB + t] : 0;
  int incl = a;
#pragma unroll
  for (int off = 1; off < 64; off <<= 1) {
    int u = __shfl_up(incl, off);
    if (lane >= off) incl += u;
  }
  __shared__ int wsum[4];
  if (lane == 63) wsum[wid] = incl;
  __syncthreads();
  int wo = 0;
#pragma unroll
  for (int w = 0; w < 4; ++w)
    if (w < wid) wo += wsum[w];
  int excl = wo + incl - a;
  if (t < CB) rowoff[k * CB + t] = excl;
  if (t == CB - 1) rowtot[k] = excl + a;
}

// ------------------- S2: exclusive scan of bucket totals -------------------
__global__ void s2_kernel(const int* __restrict__ rowtot, int* __restrict__ rowbase,
                          int NBUKr) {
  const int t = threadIdx.x;
  const int lane = t & 63, wid = t >> 6;
  int a = (t < NBUKr) ? rowtot[t] : 0;
  int incl = a;
#pragma unroll
  for (int off = 1; off < 64; off <<= 1) {
    int u = __shfl_up(incl, off);
    if (lane >= off) incl += u;
  }
  __shared__ int wsum[4];
  if (lane == 63) wsum[wid] = incl;
  __syncthreads();
  int wo = 0;
#pragma unroll
  for (int w = 0; w < 4; ++w)
    if (w < wid) wo += wsum[w];
  int excl = wo + incl - a;
  if (t < NBUKr) rowbase[t] = excl;
  if (t == NBUKr - 1) rowbase[NBUKr] = excl + a;
}

// --------------------------- GEMM body (device) ----------------------------
// C[M,BN](bf16) = (A[M,K] @ Wt[BN,K]) [* dinv[row] if SCALE].  BM=BK=64.
template <int BN, bool A_BF16, bool SCALE>
__device__ __forceinline__ void gemm_body(const void* __restrict__ Av,
                                          const unsigned short* __restrict__ Wt,
                                          const float* __restrict__ dinv,
                                          unsigned short* __restrict__ C,
                                          int M, int K, int bid) {
  constexpr int BM = 64, BK = 64;
  constexpr int NF = BN / 32;
  __shared__ unsigned short Al[BM * BK];
  __shared__ unsigned short Bl[(BN > BM ? BN : BM) * BK];
  const int tid = threadIdx.x;
  const int lane = tid & 63;
  const int wave = tid >> 6;
  const int wm = wave >> 1, wn = wave & 1;
  const int block_row = bid * BM;

  f32x4 acc[2][NF];
#pragma unroll
  for (int i = 0; i < 2; ++i)
#pragma unroll
    for (int j = 0; j < NF; ++j) acc[i][j] = (f32x4){0.f, 0.f, 0.f, 0.f};

  for (int k0 = 0; k0 < K; k0 += BK) {
    if constexpr (!A_BF16) {
      const float* A = (const float*)Av;
      const int r = tid >> 2;
      const int c0 = (tid & 3) * 16;
      const int grow = block_row + r;
      float4 v[4];
      if (grow < M) {
        const float4* p = reinterpret_cast<const float4*>(&A[(size_t)grow * K + k0 + c0]);
        v[0] = p[0]; v[1] = p[1]; v[2] = p[2]; v[3] = p[3];
      } else {
        v[0] = v[1] = v[2] = v[3] = make_float4(0.f, 0.f, 0.f, 0.f);
      }
      unsigned short tbuf[16];
#pragma unroll
      for (int q = 0; q < 4; ++q) {
        tbuf[q * 4 + 0] = f2bf(v[q].x); tbuf[q * 4 + 1] = f2bf(v[q].y);
        tbuf[q * 4 + 2] = f2bf(v[q].z); tbuf[q * 4 + 3] = f2bf(v[q].w);
      }
#pragma unroll
      for (int h = 0; h < 2; ++h) {
        int c = c0 + h * 8;
        int byte = r * 128 + c * 2;
        byte ^= (r & 7) << 4;
        u16x8 pk;
#pragma unroll
        for (int q = 0; q < 8; ++q) pk[q] = tbuf[h * 8 + q];
        *reinterpret_cast<u16x8*>(reinterpret_cast<char*>(Al) + byte) = pk;
      }
    } else {
      const unsigned short* A = (const unsigned short*)Av;
#pragma unroll
      for (int l = 0; l < 2; ++l) {
        int vidx = tid + l * 256;
        int r = vidx >> 3;
        int kc = (vidx & 7) * 8;
        int grow = block_row + r;
        u16x8 pk = (u16x8){0, 0, 0, 0, 0, 0, 0, 0};
        if (grow < M) pk = *reinterpret_cast<const u16x8*>(&A[(size_t)grow * K + k0 + kc]);
        int byte = r * 128 + kc * 2;
        byte ^= (r & 7) << 4;
        *reinterpret_cast<u16x8*>(reinterpret_cast<char*>(Al) + byte) = pk;
      }
    }
    {
#pragma unroll
      for (int l = 0; l < (BN * BK / 8) / 256; ++l) {
        int vidx = tid + l * 256;
        int n = vidx >> 3;
        int kc = (vidx & 7) * 8;
        u16x8 pk = *reinterpret_cast<const u16x8*>(&Wt[(size_t)n * K + k0 + kc]);
        int byte = n * 128 + kc * 2;
        byte ^= (n & 7) << 4;
        *reinterpret_cast<u16x8*>(reinterpret_cast<char*>(Bl) + byte) = pk;
      }
    }
    __syncthreads();
#pragma unroll
    for (int kk = 0; kk < 2; ++kk) {
      const int kb = kk * 32 + (lane >> 4) * 8;
      bf16x8 af[2], bfr[NF];
#pragma unroll
      for (int mf = 0; mf < 2; ++mf) {
        int r = wm * 32 + mf * 16 + (lane & 15);
        int byte = r * 128 + kb * 2;
        byte ^= (r & 7) << 4;
        af[mf] = *reinterpret_cast<bf16x8*>(reinterpret_cast<char*>(Al) + byte);
      }
#pragma unroll
      for (int nf = 0; nf < NF; ++nf) {
        int n = wn * (BN / 2) + nf * 16 + (lane & 15);
        int byte = n * 128 + kb * 2;
        byte ^= (n & 7) << 4;
        bfr[nf] = *reinterpret_cast<bf16x8*>(reinterpret_cast<char*>(Bl) + byte);
      }
#pragma unroll
      for (int mf = 0; mf < 2; ++mf)
#pragma unroll
        for (int nf = 0; nf < NF; ++nf)
          acc[mf][nf] = __builtin_amdgcn_mfma_f32_16x16x32_bf16(af[mf], bfr[nf], acc[mf][nf], 0, 0, 0);
    }
    __syncthreads();
  }
#pragma unroll
  for (int mf = 0; mf < 2; ++mf) {
#pragma unroll
    for (int r = 0; r < 4; ++r) {
      int row = block_row + wm * 32 + mf * 16 + (lane >> 4) * 4 + r;
      if (row < M) {
        float dr = 1.f;
        if constexpr (SCALE) dr = dinv[row];
#pragma unroll
        for (int nf = 0; nf < NF; ++nf) {
          int colc = wn * (BN / 2) + nf * 16 + (lane & 15);
          float v = acc[mf][nf][r];
          if constexpr (SCALE) v *= dr;
          C[(size_t)row * BN + colc] = f2bf(v);
        }
      }
    }
  }
}

template <int BN, bool A_BF16, bool SCALE>
__global__ void mfma_gemm_kernel(const void* __restrict__ Av,
                                 const unsigned short* __restrict__ Wt,
                                 const float* __restrict__ dinv,
                                 unsigned short* __restrict__ C, int M, int K) {
  gemm_body<BN, A_BF16, SCALE>(Av, Wt, dinv, C, M, K, blockIdx.x);
}

// -------------- B: staged scatter into private segments (device) -----------
__device__ __forceinline__ void scatterB_body(const int* __restrict__ src,
                                              const int* __restrict__ dst,
                                              int E, int CB, int NBUKr,
                                              const int* __restrict__ rowoff,
                                              const int* __restrict__ rowbase,
                                              unsigned* __restrict__ stage, int blk) {
  __shared__ int pos[256];
  const int t = threadIdx.x;
  if (t < NBUKr) pos[t] = rowbase[t] + rowoff[t * CB + blk];
  __syncthreads();
  const int E4 = E >> 2;
  const int4* dst4 = (const int4*)dst;
  const int4* src4 = (const int4*)src;
  const int base4 = blk * (CHUNK / 4);
#pragma unroll
  for (int i = 0; i < CHUNK / 4 / 256; ++i) {
    int idx = base4 + t + i * 256;
    if (idx < E4) {
      int4 d = dst4[idx];
      int4 s = src4[idx];
      int p;
      p = atomicAdd(&pos[d.x >> 8], 1); stage[p] = ((unsigned)(d.x & 255) << 16) | (unsigned)s.x;
      p = atomicAdd(&pos[d.y >> 8], 1); stage[p] = ((unsigned)(d.y & 255) << 16) | (unsigned)s.y;
      p = atomicAdd(&pos[d.z >> 8], 1); stage[p] = ((unsigned)(d.z & 255) << 16) | (unsigned)s.z;
      p = atomicAdd(&pos[d.w >> 8], 1); stage[p] = ((unsigned)(d.w & 255) << 16) | (unsigned)s.w;
    }
  }
  if (blk == 0 && t < (E & 3)) {
    int e = (E & ~3) + t;
    int d = dst[e], s = src[e];
    int p = atomicAdd(&pos[d >> 8], 1);
    stage[p] = ((unsigned)(d & 255) << 16) | (unsigned)s;
  }
}

__global__ void gemm1_scatter_kernel(const float* __restrict__ x,
                                     const unsigned short* __restrict__ Wt1,
                                     unsigned short* __restrict__ C, int M,
                                     const int* __restrict__ src, const int* __restrict__ dst,
                                     int E, int CB, int NBUKr,
                                     const int* __restrict__ rowoff,
                                     const int* __restrict__ rowbase,
                                     unsigned* __restrict__ stage) {
  if ((int)blockIdx.x < CB) {
    scatterB_body(src, dst, E, CB, NBUKr, rowoff, rowbase, stage, blockIdx.x);
  } else {
    gemm_body<128, false, false>(x, Wt1, nullptr, C, M, NFEAT, blockIdx.x - CB);
  }
}

// ------------- C: per-bucket node sort -> row ranges, col, dinv ------------
__global__ void phaseC_kernel(const unsigned* __restrict__ stage,
                              const int* __restrict__ rowbase,
                              int* __restrict__ row_beg, int* __restrict__ row_end,
                              unsigned short* __restrict__ col, float* __restrict__ dinv,
                              int N) {
  const int k = blockIdx.x;
  const int start = rowbase[k];
  const int cnt = rowbase[k + 1] - start;
  const int node0 = k << 8;
  const int t = threadIdx.x;
  __shared__ int hist[256], lpos[256], wsum[4];
  __shared__ unsigned stash[CAPC];
  hist[t] = 0;
  __syncthreads();
  for (int i = t; i < cnt; i += 256) {
    unsigned v = stage[start + i];
    if (i < CAPC) stash[i] = v;
    atomicAdd(&hist[v >> 16], 1);
  }
  __syncthreads();
  int a = hist[t];
  const int lane = t & 63, wid = t >> 6;
  int incl = a;
#pragma unroll
  for (int off = 1; off < 64; off <<= 1) {
    int u = __shfl_up(incl, off);
    if (lane >= off) incl += u;
  }
  if (lane == 63) wsum[wid] = incl;
  __syncthreads();
  int wo = 0;
#pragma unroll
  for (int w = 0; w < 4; ++w)
    if (w < wid) wo += wsum[w];
  int excl = wo + incl - a;
  lpos[t] = excl;
  int node = node0 + t;
  if (node < N) {
    row_beg[node] = start + excl;
    row_end[node] = start + excl + a;
    dinv[node] = rsqrtf((float)(a + 1));
  }
  __syncthreads();
  for (int i = t; i < cnt; i += 256) {
    unsigned v = (i < CAPC) ? stash[i] : stage[start + i];
    int p = atomicAdd(&lpos[v >> 16], 1);
    col[start + p] = (unsigned short)(v & 0xFFFFu);
  }
}

// ----------------------------- aggregation ---------------------------------
// 1 wave/node, LPN=F/8 lanes per edge-row, SLOTS=64/LPN.
// WEIGHTED: out = di*( sum_j dinv[col_j]*z[col_j] + di*z[i] ) + b
// else (z pre-scaled): out = di*( sum_j z'[col_j] + z'[i] ) + b
template <int F, int RELU, bool OUT_BF16, bool WEIGHTED>
__global__ void agg_kernel(const unsigned short* __restrict__ H,
                           const int* __restrict__ row_beg, const int* __restrict__ row_end,
                           const unsigned short* __restrict__ col,
                           const float* __restrict__ dinv, const float* __restrict__ bias,
                           void* __restrict__ out, int N) {
  constexpr int LPN = F / 8;
  constexpr int SLOTS = 64 / LPN;
  const int tid = threadIdx.x;
  const int lane = tid & 63;
  const int li = lane & (LPN - 1);
  const int slot = lane / LPN;
  const int node = blockIdx.x * 4 + (tid >> 6);
  if (node >= N) return;
  const float di = dinv[node];
  const u16x8* Hv = reinterpret_cast<const u16x8*>(H);
  u16x8 h0 = Hv[(size_t)node * LPN + li];

  float s[8];
#pragma unroll
  for (int q = 0; q < 8; ++q) s[q] = 0.f;

  const int beg = row_beg[node];
  const int end = row_end[node];
  int j = beg + slot;
  for (; j + 3 * SLOTS < end; j += 4 * SLOTS) {
    int i0 = col[j], i1 = col[j + SLOTS], i2 = col[j + 2 * SLOTS], i3 = col[j + 3 * SLOTS];
    float w0 = 1.f, w1 = 1.f, w2 = 1.f, w3 = 1.f;
    if constexpr (WEIGHTED) { w0 = dinv[i0]; w1 = dinv[i1]; w2 = dinv[i2]; w3 = dinv[i3]; }
    u16x8 r0 = Hv[(size_t)i0 * LPN + li];
    u16x8 r1 = Hv[(size_t)i1 * LPN + li];
    u16x8 r2 = Hv[(size_t)i2 * LPN + li];
    u16x8 r3 = Hv[(size_t)i3 * LPN + li];
    if constexpr (WEIGHTED) {
#pragma unroll
      for (int q = 0; q < 8; ++q)
        s[q] += bf2f(r0[q]) * w0 + bf2f(r1[q]) * w1 + bf2f(r2[q]) * w2 + bf2f(r3[q]) * w3;
    } else {
#pragma unroll
      for (int q = 0; q < 8; ++q)
        s[q] += (bf2f(r0[q]) + bf2f(r1[q])) + (bf2f(r2[q]) + bf2f(r3[q]));
    }
  }
  for (; j < end; j += SLOTS) {
    int i0 = col[j];
    float w0 = 1.f;
    if constexpr (WEIGHTED) w0 = dinv[i0];
    u16x8 r0 = Hv[(size_t)i0 * LPN + li];
    if constexpr (WEIGHTED) {
#pragma unroll
      for (int q = 0; q < 8; ++q) s[q] += bf2f(r0[q]) * w0;
    } else {
#pragma unroll
      for (int q = 0; q < 8; ++q) s[q] += bf2f(r0[q]);
    }
  }
#pragma unroll
  for (int off = LPN; off < 64; off <<= 1) {
#pragma unroll
    for (int q = 0; q < 8; ++q) s[q] += __shfl_xor(s[q], off);
  }
  if (slot == 0) {
    const float4* bv = reinterpret_cast<const float4*>(bias) + li * 2;
    float4 b0 = bv[0], b1 = bv[1];
    float sv[8];
#pragma unroll
    for (int q = 0; q < 8; ++q) {
      float self = WEIGHTED ? bf2f(h0[q]) * di : bf2f(h0[q]);
      sv[q] = (s[q] + self) * di;
    }
    sv[0] += b0.x; sv[1] += b0.y; sv[2] += b0.z; sv[3] += b0.w;
    sv[4] += b1.x; sv[5] += b1.y; sv[6] += b1.z; sv[7] += b1.w;
    if (RELU) {
#pragma unroll
      for (int q = 0; q < 8; ++q) sv[q] = fmaxf(sv[q], 0.f);
    }
    if constexpr (OUT_BF16) {
      u16x8 pk;
#pragma unroll
      for (int q = 0; q < 8; ++q) pk[q] = f2bf(sv[q]);
      reinterpret_cast<u16x8*>(out)[(size_t)node * LPN + li] = pk;
    } else {
      float4* ov = reinterpret_cast<float4*>(out) + (size_t)node * LPN * 2 + li * 2;
      ov[0] = make_float4(sv[0], sv[1], sv[2], sv[3]);
      ov[1] = make_float4(sv[4], sv[5], sv[6], sv[7]);
    }
  }
}

// ----------------- fused agg (F=64) + log_softmax --------------------------
__global__ void agg_ls_kernel(const unsigned short* __restrict__ H,
                              const int* __restrict__ row_beg, const int* __restrict__ row_end,
                              const unsigned short* __restrict__ col,
                              const float* __restrict__ dinv, const float* __restrict__ bias,
                              float* __restrict__ out, int N) {
  constexpr int LPN = 8;
  constexpr int SLOTS = 8;
  const int tid = threadIdx.x;
  const int lane = tid & 63;
  const int li = lane & (LPN - 1);
  const int slot = lane / LPN;
  const int node = blockIdx.x * 4 + (tid >> 6);
  if (node >= N) return;
  const float di = dinv[node];
  const u16x8* Hv = reinterpret_cast<const u16x8*>(H);
  u16x8 h0 = Hv[(size_t)node * LPN + li];

  float s[8];
#pragma unroll
  for (int q = 0; q < 8; ++q) s[q] = 0.f;

  const int beg = row_beg[node];
  const int end = row_end[node];
  int j = beg + slot;
  for (; j + 3 * SLOTS < end; j += 4 * SLOTS) {
    int i0 = col[j], i1 = col[j + SLOTS], i2 = col[j + 2 * SLOTS], i3 = col[j + 3 * SLOTS];
    u16x8 r0 = Hv[(size_t)i0 * LPN + li];
    u16x8 r1 = Hv[(size_t)i1 * LPN + li];
    u16x8 r2 = Hv[(size_t)i2 * LPN + li];
    u16x8 r3 = Hv[(size_t)i3 * LPN + li];
#pragma unroll
    for (int q = 0; q < 8; ++q)
      s[q] += (bf2f(r0[q]) + bf2f(r1[q])) + (bf2f(r2[q]) + bf2f(r3[q]));
  }
  for (; j < end; j += SLOTS) {
    int i0 = col[j];
    u16x8 r0 = Hv[(size_t)i0 * LPN + li];
#pragma unroll
    for (int q = 0; q < 8; ++q) s[q] += bf2f(r0[q]);
  }
#pragma unroll
  for (int off = LPN; off < 64; off <<= 1) {
#pragma unroll
    for (int q = 0; q < 8; ++q) s[q] += __shfl_xor(s[q], off);
  }
  float v[8];
  const float4* bv = reinterpret_cast<const float4*>(bias) + li * 2;
  float4 b0 = bv[0], b1 = bv[1];
#pragma unroll
  for (int q = 0; q < 8; ++q) v[q] = (s[q] + bf2f(h0[q])) * di;
  v[0] += b0.x; v[1] += b0.y; v[2] += b0.z; v[3] += b0.w;
  v[4] += b1.x; v[5] += b1.y; v[6] += b1.z; v[7] += b1.w;
  float m = v[0];
#pragma unroll
  for (int q = 1; q < 8; ++q) m = fmaxf(m, v[q]);
#pragma unroll
  for (int off = 1; off < 8; off <<= 1) m = fmaxf(m, __shfl_xor(m, off));
  float es = 0.f;
#pragma unroll
  for (int q = 0; q < 8; ++q) es += expf(v[q] - m);
#pragma unroll
  for (int off = 1; off < 8; off <<= 1) es += __shfl_xor(es, off);
  if (slot == 0) {
    float lse = m + logf(es);
    float4* ov = reinterpret_cast<float4*>(out) + (size_t)node * 16 + li * 2;
    ov[0] = make_float4(v[0] - lse, v[1] - lse, v[2] - lse, v[3] - lse);
    ov[1] = make_float4(v[4] - lse, v[5] - lse, v[6] - lse, v[7] - lse);
  }
}

// ---------------------------------------------------------------------------
extern "C" void kernel_launch(void* const* d_in, const int* in_sizes, int n_in,
                              void* d_out, int out_size, void* d_ws, size_t ws_size,
                              hipStream_t stream) {
  const float* x  = (const float*)d_in[0];
  const int*   ei = (const int*)d_in[1];
  const float* W1 = (const float*)d_in[2];
  const float* b1 = (const float*)d_in[3];
  const float* W2 = (const float*)d_in[4];
  const float* b2 = (const float*)d_in[5];
  const float* W3 = (const float*)d_in[6];
  const float* b3 = (const float*)d_in[7];
  float* out = (float*)d_out;

  const int N = in_sizes[0] / NFEAT;  // 50000
  const int E = in_sizes[1] / 2;      // 800000
  const int* src = ei;
  const int* dst = ei + E;

  const int NBUKr = (N + 255) >> 8;            // 196 buckets (dst>>8)
  const int CB    = (E + CHUNK - 1) / CHUNK;   // 196 chunk blocks

  char* ws = (char*)d_ws;
  size_t off = 0;
  auto nxt = [&](size_t bytes) -> void* {
    void* p = ws + off;
    off += (bytes + 255) & ~(size_t)255;
    return p;
  };
  int*      Gh      = (int*)nxt((size_t)NBUKr * CB * 4);
  int*      rowoff  = (int*)nxt((size_t)NBUKr * CB * 4);
  int*      rowtot  = (int*)nxt((size_t)NBUKr * 4);
  int*      rowbase = (int*)nxt((size_t)(NBUKr + 1) * 4);
  unsigned* stage   = (unsigned*)nxt((size_t)E * 4);
  int*      row_beg = (int*)nxt((size_t)N * 4);
  int*      row_end = (int*)nxt((size_t)N * 4);
  unsigned short* col = (unsigned short*)nxt((size_t)E * 2);
  float*    dinv    = (float*)nxt((size_t)N * 4);
  unsigned short* zbuf = (unsigned short*)nxt((size_t)N * NHID * 2);
  unsigned short* hb16 = (unsigned short*)nxt((size_t)N * NHID * 2);
  unsigned short* Wt1 = (unsigned short*)nxt((size_t)NHID * NFEAT * 2);
  unsigned short* Wt2 = (unsigned short*)nxt((size_t)NHID * NHID * 2);
  unsigned short* Wt3 = (unsigned short*)nxt((size_t)NCLS * NHID * 2);
  (void)ws_size; (void)n_in; (void)out_size;

  const int GB = (N + 63) / 64;    // 782 GEMM blocks (BM=64)
  const int ablocks = (N + 3) / 4;

  // A: chunk histograms + wcast riders
  histA_wcast_kernel<<<CB + 256 + 64 + 32, 256, 0, stream>>>(
      dst, E, CB, NBUKr, Gh, W1, Wt1, W2, Wt2, W3, Wt3);
  // S1/S2: segment bases
  s1_kernel<<<NBUKr, 256, 0, stream>>>(Gh, rowoff, rowtot, CB);
  s2_kernel<<<1, 256, 0, stream>>>(rowtot, rowbase, NBUKr);
  // B (scatter into private segments) fused with GEMM1 (unscaled)
  gemm1_scatter_kernel<<<CB + GB, 256, 0, stream>>>(
      x, Wt1, zbuf, N, src, dst, E, CB, NBUKr, rowoff, rowbase, stage);
  // C: per-bucket finalize -> row ranges, col(u16), dinv
  phaseC_kernel<<<NBUKr, 256, 0, stream>>>(stage, rowbase, row_beg, row_end, col, dinv, N);

  // layer 1 (weighted agg: z unscaled, dinv[col] gather L2-hot)
  agg_kernel<128, 1, true, true><<<ablocks, 256, 0, stream>>>(
      zbuf, row_beg, row_end, col, dinv, b1, hb16, N);
  // layer 2
  mfma_gemm_kernel<128, true, true><<<GB, 256, 0, stream>>>(hb16, Wt2, dinv, zbuf, N, NHID);
  agg_kernel<128, 1, true, false><<<ablocks, 256, 0, stream>>>(
      zbuf, row_beg, row_end, col, dinv, b2, hb16, N);
  // layer 3
  mfma_gemm_kernel<64, true, true><<<GB, 256, 0, stream>>>(hb16, Wt3, dinv, zbuf, N, NHID);
  agg_ls_kernel<<<ablocks, 256, 0, stream>>>(zbuf, row_beg, row_end, col, dinv, b3, out, N);
}